// Round 3
// baseline (1221.993 us; speedup 1.0000x reference)
//
#include <hip/hip_runtime.h>
#include <stdint.h>

#define HD 2048
#define NTOK 4096
#define NROUTED 7
#define NEXP 8
#define ROWS_ROUTED 8192   // 2*NTOK (top-2, exact)
#define ROWS_TOTAL 12288   // + shared 4096
#define ROWS_PAD 12416     // +128 slack for tile overshoot

#define BM 256
#define BN 256
#define BK 32
#define NT (HD / BK)       // 64 K-tiles

typedef __attribute__((ext_vector_type(8))) __bf16 bf16x8;
typedef __attribute__((ext_vector_type(4))) float f32x4;
typedef __attribute__((ext_vector_type(8))) unsigned short u16x8;

__device__ __forceinline__ float bf2f(unsigned short h) {
  union { unsigned int u; float f; } x; x.u = ((unsigned int)h) << 16; return x.f;
}
__device__ __forceinline__ unsigned short f2bf(float f) {
  union { float f; unsigned int u; } x; x.f = f;
  unsigned int r = x.u + 0x7fffu + ((x.u >> 16) & 1u);   // RNE
  return (unsigned short)(r >> 16);
}

// ---- async global->LDS, 16B/lane. LDS dest is wave-uniform base + lane*16.
__device__ __forceinline__ void async16(const void* g, void* l) {
  __builtin_amdgcn_global_load_lds(
      (__attribute__((address_space(1))) const void*)(uintptr_t)g,
      (__attribute__((address_space(3))) void*)(unsigned int)(uintptr_t)l,
      16, 0, 0);
}

// ---------------- elementwise fp32 -> bf16 ----------------
__global__ __launch_bounds__(256) void k_convert_bf16(const float* __restrict__ in,
                                                      unsigned short* __restrict__ out, int n) {
  int i = (blockIdx.x * 256 + threadIdx.x) * 4;
  if (i >= n) return;
  float4 v = *(const float4*)(in + i);
  ushort4 o; o.x = f2bf(v.x); o.y = f2bf(v.y); o.z = f2bf(v.z); o.w = f2bf(v.w);
  *(ushort4*)(out + i) = o;
}

// ---------------- transpose + convert: 8 matrices in one launch (z<7 routed, z==7 shared)
// in [2048][2048] f32 -> out = in^T bf16. 64x64 tile, 256 threads (16x16).
__global__ __launch_bounds__(256) void k_transpose_bf16(const float* __restrict__ inR,
                                                        const float* __restrict__ inS,
                                                        unsigned short* __restrict__ outR,
                                                        unsigned short* __restrict__ outS) {
  __shared__ float tile[64][65];
  const size_t bs = (size_t)HD * HD;
  int z = blockIdx.z;
  const float* in = (z < NROUTED) ? (inR + (size_t)z * bs) : inS;
  unsigned short* out = (z < NROUTED) ? (outR + (size_t)z * bs) : outS;
  int tx = threadIdx.x & 15, ty = threadIdx.x >> 4;   // 16 x 16
  int r0 = blockIdx.y * 64, c0 = blockIdx.x * 64;
  #pragma unroll
  for (int i = 0; i < 4; i++) {
    float4 v = *(const float4*)(in + (size_t)(r0 + ty + 16 * i) * HD + c0 + tx * 4);
    tile[ty + 16 * i][tx * 4 + 0] = v.x;
    tile[ty + 16 * i][tx * 4 + 1] = v.y;
    tile[ty + 16 * i][tx * 4 + 2] = v.z;
    tile[ty + 16 * i][tx * 4 + 3] = v.w;
  }
  __syncthreads();
  #pragma unroll
  for (int i = 0; i < 4; i++) {
    int orow = ty + 16 * i;          // output row = c0+orow
    int oc = tx * 4;                 // output cols r0+oc..+3
    ushort4 o;
    o.x = f2bf(tile[oc + 0][orow]);
    o.y = f2bf(tile[oc + 1][orow]);
    o.z = f2bf(tile[oc + 2][orow]);
    o.w = f2bf(tile[oc + 3][orow]);
    *(ushort4*)(out + (size_t)(c0 + orow) * HD + r0 + oc) = o;
  }
}

// ---------------- router: gate = x@Wr + br; top-2 on gate+gate_bias; softmax of selected logits
__global__ __launch_bounds__(256) void k_router(const float* __restrict__ x, const float* __restrict__ Wr,
                                                const float* __restrict__ br, const float* __restrict__ gbias,
                                                int* __restrict__ ids, float* __restrict__ wts,
                                                int* __restrict__ ctrl) {
  int lane = threadIdx.x & 63, wid = threadIdx.x >> 6;
  int t = blockIdx.x * 4 + wid;
  const float* xr = x + (size_t)t * HD;
  float acc[NROUTED];
  #pragma unroll
  for (int e = 0; e < NROUTED; e++) acc[e] = 0.f;
  for (int k = lane; k < HD; k += 64) {
    float xv = xr[k];
    const float* wrow = Wr + k * NROUTED;
    #pragma unroll
    for (int e = 0; e < NROUTED; e++) acc[e] += xv * wrow[e];
  }
  #pragma unroll
  for (int e = 0; e < NROUTED; e++) {
    #pragma unroll
    for (int off = 32; off > 0; off >>= 1) acc[e] += __shfl_down(acc[e], off);
  }
  if (lane == 0) {
    float lg[NROUTED], bg[NROUTED];
    #pragma unroll
    for (int e = 0; e < NROUTED; e++) { lg[e] = acc[e] + br[e]; bg[e] = lg[e] + gbias[e]; }
    int i1 = 0;
    #pragma unroll
    for (int e = 1; e < NROUTED; e++) if (bg[e] > bg[i1]) i1 = e;
    int i2 = (i1 == 0) ? 1 : 0;
    #pragma unroll
    for (int e = 0; e < NROUTED; e++) if (e != i1 && bg[e] > bg[i2]) i2 = e;
    float l1 = lg[i1], l2 = lg[i2];
    float m = fmaxf(l1, l2);
    float p1 = __expf(l1 - m), p2 = __expf(l2 - m);
    float s = p1 + p2;
    ids[2*t] = i1; ids[2*t+1] = i2;
    wts[2*t] = p1 / s; wts[2*t+1] = p2 / s;
    atomicAdd(&ctrl[i1], 1); atomicAdd(&ctrl[i2], 1);
  }
}

__global__ void k_offsets(int* ctrl) {
  if (threadIdx.x == 0 && blockIdx.x == 0) {
    ctrl[7] = NTOK;
    int o = 0;
    #pragma unroll
    for (int e = 0; e < NEXP; e++) { ctrl[8 + e] = o; o += ctrl[e]; }
  }
}

__global__ __launch_bounds__(256) void k_build_lists(const int* __restrict__ ids, int* __restrict__ ctrl,
                                                     int* __restrict__ tok_list, int* __restrict__ tok_pos) {
  int t = blockIdx.x * 256 + threadIdx.x;
  if (t >= NTOK) return;
  #pragma unroll
  for (int j = 0; j < 2; j++) {
    int e = ids[2*t + j];
    int pos = ctrl[8 + e] + atomicAdd(&ctrl[16 + e], 1);
    tok_list[pos] = t;
    tok_pos[2*t + j] = pos;
  }
  tok_list[ROWS_ROUTED + t] = t;
}

// ---------------- grouped GEMM: 256x256 tile, BK=32, 8 waves (wave-tile 128x64, m201
// geometry), static 64KiB double-buffered LDS, COUNTED vmcnt pipeline (2 tiles in
// flight, raw s_barrier -- never drains the prefetch), bank-conflict-free XOR swizzle
// (slot' = slot ^ ((row>>1)&3); row parity supplies the other bank bit at 64B rows).
//
// Pipeline invariant: before compute(t), each wave waits vmcnt(4) -> its own 4 loads
// for tile t (the oldest outstanding) have landed; the barrier then aggregates across
// waves. Tile t+1's 4 loads stay in flight across the barrier. STAGE(t+2) is issued
// only after barrier2 (all reads of that buffer completed before barrier2 by lgkmcnt
// data-dependency of the MFMAs).
//
// MODE 0: u  = gather(x) @ WupT  + bup
// MODE 1: g  = silu(u @ WgateT + bgate) * u
// MODE 2: eo = g @ WdownT + bdown

#define STAGE(bufp)                                                       \
  { unsigned short* _a = &sm[bufp][0][0];                                 \
    unsigned short* _b = &sm[bufp][1][0];                                 \
    _Pragma("unroll")                                                     \
    for (int r = 0; r < 2; r++) {                                         \
      async16(pA[r], _a + r * 4096 + wid * 512); pA[r] += BK;             \
      async16(pB[r], _b + r * 4096 + wid * 512); pB[r] += BK;             \
    } }

template<int MODE>
__global__ __launch_bounds__(512, 2) void k_moe_gemm(
    const unsigned short* __restrict__ Abase,
    const unsigned short* __restrict__ WTr,   // [7][N=2048][K=2048] bf16 (pre-transposed)
    const unsigned short* __restrict__ WTs,   // [2048][2048]
    const float* __restrict__ biasR,
    const float* __restrict__ biasS,
    const int* __restrict__ ctrl,
    const int* __restrict__ tok_list,
    const unsigned short* __restrict__ Uep,   // u (MODE 1 only)
    unsigned short* __restrict__ Out)         // bf16 [ROWS_PAD][2048]
{
  const int e   = blockIdx.z;
  const int cnt = ctrl[e];
  const int m0  = blockIdx.y * BM;
  if (m0 >= cnt) return;
  const int off = ctrl[8 + e];
  const int n0  = blockIdx.x * BN;

  const unsigned short* W = (e < NROUTED) ? (WTr + (size_t)e * HD * HD) : WTs;
  const float* bias = (e < NROUTED) ? (biasR + e * HD) : biasS;

  // [buf][A|B][256 rows x 32 bf16] = 2*2*16KiB = 64KiB static
  __shared__ __align__(16) unsigned short sm[2][2][BM * BK];

  const int tid  = threadIdx.x;
  const int lane = tid & 63;
  const int wid  = tid >> 6;        // 8 waves

  // ---- staging: sweep r covers local row r*128 + tid/4, slot tid&3 (16B units).
  // LDS dest is exactly linear (slot*16 + row*64 == tid*16); global source chunk is
  // pre-swizzled: chunk = slot ^ ((row>>1)&3)  [involution, matches read side].
  const int srow = tid >> 2;               // 0..127
  const int sslot = tid & 3;
  const int csw = (sslot ^ ((srow >> 1) & 3)) * 8;   // ushort offset within row
  const unsigned short* pA[2];
  const unsigned short* pB[2];
  #pragma unroll
  for (int r = 0; r < 2; r++) {
    int row = r * 128 + srow;              // tile-local row 0..255
    size_t ga;
    if (MODE == 0) {
      int mr = m0 + row; if (mr >= cnt) mr = cnt - 1;
      ga = (size_t)tok_list[off + mr] * HD;
    } else {
      ga = (size_t)(off + m0 + row) * HD;
    }
    pA[r] = Abase + ga + csw;
    pB[r] = W + (size_t)(n0 + row) * HD + csw;
  }

  // ---- fragment geometry: wave-tile 128x64 (2 wave-rows x 4 wave-cols)
  const int wr   = wid >> 2;            // 0..1
  const int wc   = wid & 3;             // 0..3
  const int rm   = lane & 15;
  const int q    = lane >> 4;           // k-quad 0..3
  // read-side swizzle: slot' = q ^ ((row>>1)&3); all fragment row-bases are mult of 16
  // so (row>>1)&3 == (rm>>1)&3 for every mi/ni.
  const int qx   = (q ^ ((rm >> 1) & 3)) * 8;   // ushort offset of 16B chunk

  f32x4 acc[8][4];
  f32x4 zero = {0.f, 0.f, 0.f, 0.f};
  #pragma unroll
  for (int i = 0; i < 8; i++)
    #pragma unroll
    for (int j = 0; j < 4; j++) acc[i][j] = zero;

  STAGE(0);                              // tile 0 -> buf0 (4 loads/thread)
  STAGE(1);                              // tile 1 -> buf1 (8 outstanding)

  for (int t = 0; t < NT; ++t) {
    const int buf = t & 1;
    if (t < NT - 1) { asm volatile("s_waitcnt vmcnt(4)" ::: "memory"); }  // tile t landed; t+1 in flight
    else           { asm volatile("s_waitcnt vmcnt(0)" ::: "memory"); }
    __builtin_amdgcn_s_barrier();        // all waves' tile-t staging visible
    __builtin_amdgcn_sched_barrier(0);

    const unsigned short* _ab = &sm[buf][0][0];
    const unsigned short* _bb = &sm[buf][1][0];
    bf16x8 af[8], bfr[4];
    #pragma unroll
    for (int mi = 0; mi < 8; mi++)
      af[mi] = *(const bf16x8*)(_ab + (wr * 128 + mi * 16 + rm) * BK + qx);
    #pragma unroll
    for (int ni = 0; ni < 4; ni++)
      bfr[ni] = *(const bf16x8*)(_bb + (wc * 64 + ni * 16 + rm) * BK + qx);
    #pragma unroll
    for (int mi = 0; mi < 8; mi++)
      #pragma unroll
      for (int ni = 0; ni < 4; ni++)
        acc[mi][ni] = __builtin_amdgcn_mfma_f32_16x16x32_bf16(af[mi], bfr[ni], acc[mi][ni], 0, 0, 0);

    __builtin_amdgcn_sched_barrier(0);
    __builtin_amdgcn_s_barrier();        // all waves done reading buf -> safe to overwrite
    __builtin_amdgcn_sched_barrier(0);
    if (t + 2 < NT) STAGE(buf);          // prefetch tile t+2 into the buffer just freed
  }

  // epilogue: C/D layout col=lane&15, row=(lane>>4)*4+reg  [verified m89/m91]
  #pragma unroll
  for (int mi = 0; mi < 8; mi++) {
    int rb = wr * 128 + mi * 16 + q * 4;
    #pragma unroll
    for (int r = 0; r < 4; r++) {
      int gm = m0 + rb + r;
      if (gm < cnt) {
        size_t orow = (size_t)(off + gm) * HD;
        #pragma unroll
        for (int ni = 0; ni < 4; ni++) {
          int gn = n0 + wc * 64 + ni * 16 + rm;
          float v = acc[mi][ni][r] + bias[gn];
          if (MODE == 1) {
            float uv = bf2f(Uep[orow + gn]);
            float sg = v / (1.f + __expf(-v));   // silu
            v = sg * uv;
          }
          Out[orow + gn] = f2bf(v);
        }
      }
    }
  }
}

// ---------------- combine: out[t] = w0*eo[p0] + w1*eo[p1] + eo[8192+t]
__global__ __launch_bounds__(256) void k_combine(const unsigned short* __restrict__ eo,
                                                 const int* __restrict__ tok_pos,
                                                 const float* __restrict__ wts,
                                                 float* __restrict__ out) {
  int t = blockIdx.x;
  int h = threadIdx.x * 8;
  int p0 = tok_pos[2*t], p1 = tok_pos[2*t+1];
  float w0 = wts[2*t], w1 = wts[2*t+1];
  u16x8 a = *(const u16x8*)(eo + (size_t)p0 * HD + h);
  u16x8 b = *(const u16x8*)(eo + (size_t)p1 * HD + h);
  u16x8 c = *(const u16x8*)(eo + (size_t)(ROWS_ROUTED + t) * HD + h);
  float* o = out + (size_t)t * HD + h;
  #pragma unroll
  for (int i = 0; i < 8; i++) o[i] = w0 * bf2f(a[i]) + w1 * bf2f(b[i]) + bf2f(c[i]);
}

extern "C" void kernel_launch(void* const* d_in, const int* in_sizes, int n_in,
                              void* d_out, int out_size, void* d_ws, size_t ws_size,
                              hipStream_t stream) {
  (void)in_sizes; (void)n_in; (void)out_size; (void)ws_size;
  const float* x     = (const float*)d_in[0];
  const float* Wr    = (const float*)d_in[1];
  const float* br    = (const float*)d_in[2];
  const float* gbias = (const float*)d_in[3];
  const float* Wup   = (const float*)d_in[4];
  const float* bup   = (const float*)d_in[5];
  const float* Wgate = (const float*)d_in[6];
  const float* bgate = (const float*)d_in[7];
  const float* Wdown = (const float*)d_in[8];
  const float* bdown = (const float*)d_in[9];
  const float* Wsu   = (const float*)d_in[10];
  const float* bsu   = (const float*)d_in[11];
  const float* Wsg   = (const float*)d_in[12];
  const float* bsg   = (const float*)d_in[13];
  const float* Wsd   = (const float*)d_in[14];
  const float* bsd   = (const float*)d_in[15];
  float* out = (float*)d_out;

  char* ws = (char*)d_ws;
  size_t o = 0;
  auto alloc = [&](size_t bytes) { char* p = ws + o; o += (bytes + 255) & ~(size_t)255; return p; };
  unsigned short* WT_r = (unsigned short*)alloc((size_t)7 * HD * HD * 2);
  unsigned short* WT_s = (unsigned short*)alloc((size_t)HD * HD * 2);
  unsigned short* xbf  = (unsigned short*)alloc((size_t)NTOK * HD * 2);
  unsigned short* bufU = (unsigned short*)alloc((size_t)ROWS_PAD * HD * 2);
  unsigned short* bufG = (unsigned short*)alloc((size_t)ROWS_PAD * HD * 2);
  int*   ctrl     = (int*)alloc(4096);
  int*   ids      = (int*)alloc(NTOK * 2 * 4);
  float* wts      = (float*)alloc(NTOK * 2 * 4);
  int*   tok_list = (int*)alloc(ROWS_TOTAL * 4);
  int*   tok_pos  = (int*)alloc(NTOK * 2 * 4);

  hipMemsetAsync(ctrl, 0, 96, stream);
  k_convert_bf16<<<NTOK * HD / 1024, 256, 0, stream>>>(x, xbf, NTOK * HD);
  k_router<<<NTOK / 4, 256, 0, stream>>>(x, Wr, br, gbias, ids, wts, ctrl);
  k_offsets<<<1, 64, 0, stream>>>(ctrl);
  k_build_lists<<<NTOK / 256, 256, 0, stream>>>(ids, ctrl, tok_list, tok_pos);

  dim3 tgrid(HD / 64, HD / 64, NEXP);
  dim3 ggrid(HD / BN, 4096 / BM, NEXP);   // x: 8 N-panels, y: 16 M-tiles, z: experts

  k_transpose_bf16<<<tgrid, 256, 0, stream>>>(Wup, Wsu, WT_r, WT_s);
  k_moe_gemm<0><<<ggrid, 512, 0, stream>>>(xbf, WT_r, WT_s, bup, bsu, ctrl, tok_list, nullptr, bufU);

  k_transpose_bf16<<<tgrid, 256, 0, stream>>>(Wgate, Wsg, WT_r, WT_s);
  k_moe_gemm<1><<<ggrid, 512, 0, stream>>>(bufU, WT_r, WT_s, bgate, bsg, ctrl, tok_list, bufU, bufG);

  k_transpose_bf16<<<tgrid, 256, 0, stream>>>(Wdown, Wsd, WT_r, WT_s);
  k_moe_gemm<2><<<ggrid, 512, 0, stream>>>(bufG, WT_r, WT_s, bdown, bsd, ctrl, tok_list, nullptr, bufU);

  k_combine<<<NTOK, 256, 0, stream>>>(bufU, tok_pos, wts, out);
}

// Round 4
// 1138.502 us; speedup vs baseline: 1.0733x; 1.0733x over previous
//
#include <hip/hip_runtime.h>
#include <stdint.h>

#define HD 2048
#define NTOK 4096
#define NROUTED 7
#define NEXP 8
#define ROWS_ROUTED 8192   // 2*NTOK (top-2, exact)
#define ROWS_TOTAL 12288   // + shared 4096
#define ROWS_PAD 12416     // +128 slack for tile overshoot

#define BM 256
#define BN 256
#define BK 64
#define NT (HD / BK)       // 32 K-tiles

typedef __attribute__((ext_vector_type(8))) __bf16 bf16x8;
typedef __attribute__((ext_vector_type(4))) float f32x4;
typedef __attribute__((ext_vector_type(8))) unsigned short u16x8;

__device__ __forceinline__ float bf2f(unsigned short h) {
  union { unsigned int u; float f; } x; x.u = ((unsigned int)h) << 16; return x.f;
}
__device__ __forceinline__ unsigned short f2bf(float f) {
  union { float f; unsigned int u; } x; x.f = f;
  unsigned int r = x.u + 0x7fffu + ((x.u >> 16) & 1u);   // RNE
  return (unsigned short)(r >> 16);
}

// ---- async global->LDS, 16B/lane. LDS dest is wave-uniform base + lane*16.
__device__ __forceinline__ void async16(const void* g, void* l) {
  __builtin_amdgcn_global_load_lds(
      (__attribute__((address_space(1))) const void*)(uintptr_t)g,
      (__attribute__((address_space(3))) void*)(unsigned int)(uintptr_t)l,
      16, 0, 0);
}

// ---------------- elementwise fp32 -> bf16 ----------------
__global__ __launch_bounds__(256) void k_convert_bf16(const float* __restrict__ in,
                                                      unsigned short* __restrict__ out, int n) {
  int i = (blockIdx.x * 256 + threadIdx.x) * 4;
  if (i >= n) return;
  float4 v = *(const float4*)(in + i);
  ushort4 o; o.x = f2bf(v.x); o.y = f2bf(v.y); o.z = f2bf(v.z); o.w = f2bf(v.w);
  *(ushort4*)(out + i) = o;
}

// ---------------- transpose + convert: 8 matrices in one launch (z<7 routed, z==7 shared)
__global__ __launch_bounds__(256) void k_transpose_bf16(const float* __restrict__ inR,
                                                        const float* __restrict__ inS,
                                                        unsigned short* __restrict__ outR,
                                                        unsigned short* __restrict__ outS) {
  __shared__ float tile[64][65];
  const size_t bs = (size_t)HD * HD;
  int z = blockIdx.z;
  const float* in = (z < NROUTED) ? (inR + (size_t)z * bs) : inS;
  unsigned short* out = (z < NROUTED) ? (outR + (size_t)z * bs) : outS;
  int tx = threadIdx.x & 15, ty = threadIdx.x >> 4;   // 16 x 16
  int r0 = blockIdx.y * 64, c0 = blockIdx.x * 64;
  #pragma unroll
  for (int i = 0; i < 4; i++) {
    float4 v = *(const float4*)(in + (size_t)(r0 + ty + 16 * i) * HD + c0 + tx * 4);
    tile[ty + 16 * i][tx * 4 + 0] = v.x;
    tile[ty + 16 * i][tx * 4 + 1] = v.y;
    tile[ty + 16 * i][tx * 4 + 2] = v.z;
    tile[ty + 16 * i][tx * 4 + 3] = v.w;
  }
  __syncthreads();
  #pragma unroll
  for (int i = 0; i < 4; i++) {
    int orow = ty + 16 * i;
    int oc = tx * 4;
    ushort4 o;
    o.x = f2bf(tile[oc + 0][orow]);
    o.y = f2bf(tile[oc + 1][orow]);
    o.z = f2bf(tile[oc + 2][orow]);
    o.w = f2bf(tile[oc + 3][orow]);
    *(ushort4*)(out + (size_t)(c0 + orow) * HD + r0 + oc) = o;
  }
}

// ---------------- router ----------------
__global__ __launch_bounds__(256) void k_router(const float* __restrict__ x, const float* __restrict__ Wr,
                                                const float* __restrict__ br, const float* __restrict__ gbias,
                                                int* __restrict__ ids, float* __restrict__ wts,
                                                int* __restrict__ ctrl) {
  int lane = threadIdx.x & 63, wid = threadIdx.x >> 6;
  int t = blockIdx.x * 4 + wid;
  const float* xr = x + (size_t)t * HD;
  float acc[NROUTED];
  #pragma unroll
  for (int e = 0; e < NROUTED; e++) acc[e] = 0.f;
  for (int k = lane; k < HD; k += 64) {
    float xv = xr[k];
    const float* wrow = Wr + k * NROUTED;
    #pragma unroll
    for (int e = 0; e < NROUTED; e++) acc[e] += xv * wrow[e];
  }
  #pragma unroll
  for (int e = 0; e < NROUTED; e++) {
    #pragma unroll
    for (int off = 32; off > 0; off >>= 1) acc[e] += __shfl_down(acc[e], off);
  }
  if (lane == 0) {
    float lg[NROUTED], bg[NROUTED];
    #pragma unroll
    for (int e = 0; e < NROUTED; e++) { lg[e] = acc[e] + br[e]; bg[e] = lg[e] + gbias[e]; }
    int i1 = 0;
    #pragma unroll
    for (int e = 1; e < NROUTED; e++) if (bg[e] > bg[i1]) i1 = e;
    int i2 = (i1 == 0) ? 1 : 0;
    #pragma unroll
    for (int e = 0; e < NROUTED; e++) if (e != i1 && bg[e] > bg[i2]) i2 = e;
    float l1 = lg[i1], l2 = lg[i2];
    float m = fmaxf(l1, l2);
    float p1 = __expf(l1 - m), p2 = __expf(l2 - m);
    float s = p1 + p2;
    ids[2*t] = i1; ids[2*t+1] = i2;
    wts[2*t] = p1 / s; wts[2*t+1] = p2 / s;
    atomicAdd(&ctrl[i1], 1); atomicAdd(&ctrl[i2], 1);
  }
}

__global__ void k_offsets(int* ctrl) {
  if (threadIdx.x == 0 && blockIdx.x == 0) {
    ctrl[7] = NTOK;
    int o = 0;
    #pragma unroll
    for (int e = 0; e < NEXP; e++) { ctrl[8 + e] = o; o += ctrl[e]; }
  }
}

__global__ __launch_bounds__(256) void k_build_lists(const int* __restrict__ ids, int* __restrict__ ctrl,
                                                     int* __restrict__ tok_list, int* __restrict__ tok_pos) {
  int t = blockIdx.x * 256 + threadIdx.x;
  if (t >= NTOK) return;
  #pragma unroll
  for (int j = 0; j < 2; j++) {
    int e = ids[2*t + j];
    int pos = ctrl[8 + e] + atomicAdd(&ctrl[16 + e], 1);
    tok_list[pos] = t;
    tok_pos[2*t + j] = pos;
  }
  tok_list[ROWS_ROUTED + t] = t;
}

// ---------------- grouped GEMM: 256x256 tile, BK=64, 8 waves (2Mx4N, wave-tile 128x64),
// m201-style 4-phase-per-K-tile schedule, 128KiB dynamic LDS double buffer, counted vmcnt
// (once per K-tile, never a hot drain), setprio around each 16-MFMA cluster, chunk-XOR
// swizzle both sides (pre-swizzled global source on write; same XOR on ds_read; LDS dest
// linear for global_load_lds).
//
// Per K-tile ledger (per thread): 8 global_load_lds (4 B-half at P3, 4 A-half at P4),
// 2 tiles in flight -> wait vmcnt(8) at tile top (vmcnt(0) at last tile).
// Slot safety: B(buf) fully consumed after P2 barrier -> stage B(t+2) in P3;
//              A(buf) fully consumed after P3 barrier -> stage A(t+2) in P4.
//
// MODE 0: u  = gather(x) @ WupT  + bup
// MODE 1: g  = silu(u @ WgateT + bgate) * u
// MODE 2: eo = g @ WdownT + bdown

#define STAGE_A(bufp)                                                     \
  { unsigned short* _d = smA + (bufp) * 16384 + wid * 512;                \
    async16(pA[0], _d);        async16(pA[1], _d + 4096);                 \
    async16(pA[2], _d + 8192); async16(pA[3], _d + 12288);                \
    pA[0] += BK; pA[1] += BK; pA[2] += BK; pA[3] += BK; }

#define STAGE_B(bufp)                                                     \
  { unsigned short* _d = smB + (bufp) * 16384 + wid * 512;                \
    async16(pB[0], _d);        async16(pB[1], _d + 4096);                 \
    async16(pB[2], _d + 8192); async16(pB[3], _d + 12288);                \
    pB[0] += BK; pB[1] += BK; pB[2] += BK; pB[3] += BK; }

#define LDA(bufp, a)                                                      \
  { const unsigned short* _p = smA + (bufp) * 16384;                      \
    _Pragma("unroll")                                                     \
    for (int mi2 = 0; mi2 < 4; mi2++) {                                   \
      _Pragma("unroll")                                                   \
      for (int ks = 0; ks < 2; ks++)                                      \
        af[mi2][ks] = *(const bf16x8*)(_p                                 \
            + (wr * 128 + (a) * 64 + mi2 * 16 + rm) * 64                  \
            + (((ks * 4 + q) ^ s7) * 8));                                 \
    } }

#define LDB(bufp, nh, dst)                                                \
  { const unsigned short* _p = smB + (bufp) * 16384;                      \
    _Pragma("unroll")                                                     \
    for (int ni2 = 0; ni2 < 2; ni2++) {                                   \
      _Pragma("unroll")                                                   \
      for (int ks = 0; ks < 2; ks++)                                      \
        dst[ni2][ks] = *(const bf16x8*)(_p                                \
            + (wc * 64 + (nh) * 32 + ni2 * 16 + rm) * 64                  \
            + (((ks * 4 + q) ^ s7) * 8));                                 \
    } }

#define MM(a, nh, Bf)                                                     \
  { _Pragma("unroll")                                                     \
    for (int mi2 = 0; mi2 < 4; mi2++) {                                   \
      _Pragma("unroll")                                                   \
      for (int ni2 = 0; ni2 < 2; ni2++) {                                 \
        acc[(a)*4+mi2][(nh)*2+ni2] = __builtin_amdgcn_mfma_f32_16x16x32_bf16( \
            af[mi2][0], Bf[ni2][0], acc[(a)*4+mi2][(nh)*2+ni2], 0, 0, 0); \
        acc[(a)*4+mi2][(nh)*2+ni2] = __builtin_amdgcn_mfma_f32_16x16x32_bf16( \
            af[mi2][1], Bf[ni2][1], acc[(a)*4+mi2][(nh)*2+ni2], 0, 0, 0); \
      } } }

template<int MODE>
__global__ __launch_bounds__(512, 2) void k_moe_gemm(
    const unsigned short* __restrict__ Abase,
    const unsigned short* __restrict__ WTr,   // [7][N=2048][K=2048] bf16 (pre-transposed)
    const unsigned short* __restrict__ WTs,   // [2048][2048]
    const float* __restrict__ biasR,
    const float* __restrict__ biasS,
    const int* __restrict__ ctrl,
    const int* __restrict__ tok_list,
    const unsigned short* __restrict__ Uep,   // u (MODE 1 only)
    unsigned short* __restrict__ Out)         // bf16 [ROWS_PAD][2048]
{
  const int e   = blockIdx.z;
  const int cnt = ctrl[e];
  const int m0  = blockIdx.y * BM;
  if (m0 >= cnt) return;
  const int off = ctrl[8 + e];
  const int n0  = blockIdx.x * BN;

  const unsigned short* W = (e < NROUTED) ? (WTr + (size_t)e * HD * HD) : WTs;
  const float* bias = (e < NROUTED) ? (biasR + e * HD) : biasS;

  extern __shared__ unsigned short smem[];   // 131072 B
  unsigned short* smA = smem;                // [2][256][64] bf16 (32768 ushorts)
  unsigned short* smB = smem + 32768;        // [2][256][64]

  const int tid  = threadIdx.x;
  const int lane = tid & 63;
  const int wid  = tid >> 6;        // 8 waves

  // ---- staging: load r covers tile row r*64 + tid/8, 16B chunk tid&7 (swizzled source).
  // Per wave the LDS dest is linear: base + lane*16 (HW-added).
  const int srow = tid >> 3;                       // 0..63
  const int csw  = ((tid & 7) ^ (srow & 7)) * 8;   // ushort offset within row
  const unsigned short* pA[4];
  const unsigned short* pB[4];
  #pragma unroll
  for (int r = 0; r < 4; r++) {
    int row = r * 64 + srow;                       // tile-local row 0..255
    size_t ga;
    if (MODE == 0) {
      int mr = m0 + row; if (mr >= cnt) mr = cnt - 1;
      ga = (size_t)tok_list[off + mr] * HD;
    } else {
      ga = (size_t)(off + m0 + row) * HD;
    }
    pA[r] = Abase + ga + csw;
    pB[r] = W + (size_t)(n0 + row) * HD + csw;
  }

  // ---- fragment geometry: wave-tile 128x64 (2 wave-rows x 4 wave-cols)
  const int wr = wid >> 2;          // 0..1
  const int wc = wid & 3;           // 0..3
  const int rm = lane & 15;
  const int q  = lane >> 4;         // k-quad 0..3
  const int s7 = rm & 7;            // fragment row-bases are multiples of 16

  f32x4 acc[8][4];
  f32x4 zero = {0.f, 0.f, 0.f, 0.f};
  #pragma unroll
  for (int i = 0; i < 8; i++)
    #pragma unroll
    for (int j = 0; j < 4; j++) acc[i][j] = zero;

  bf16x8 af[4][2], bf0[2][2], bf1[2][2];

  STAGE_A(0); STAGE_B(0);           // tile 0
  STAGE_A(1); STAGE_B(1);           // tile 1  (16 outstanding / thread)

  for (int t = 0; t < NT; ++t) {
    const int buf = t & 1;
    if (t < NT - 1) { asm volatile("s_waitcnt vmcnt(8)" ::: "memory"); }   // tile t landed
    else            { asm volatile("s_waitcnt vmcnt(0)" ::: "memory"); }
    __builtin_amdgcn_s_barrier();   // all waves' tile-t staging visible
    __builtin_amdgcn_sched_barrier(0);

    // ---- P1: read A-half(wr) lo + B lo-halves; MFMA Q(0,0)
    LDA(buf, 0); LDB(buf, 0, bf0);
    __builtin_amdgcn_s_barrier();
    asm volatile("s_waitcnt lgkmcnt(0)" ::: "memory");
    __builtin_amdgcn_sched_barrier(0);
    __builtin_amdgcn_s_setprio(1); MM(0, 0, bf0); __builtin_amdgcn_s_setprio(0);
    __builtin_amdgcn_s_barrier();

    // ---- P2: read B hi-halves; MFMA Q(0,1)
    LDB(buf, 1, bf1);
    __builtin_amdgcn_s_barrier();
    asm volatile("s_waitcnt lgkmcnt(0)" ::: "memory");
    __builtin_amdgcn_sched_barrier(0);
    __builtin_amdgcn_s_setprio(1); MM(0, 1, bf1); __builtin_amdgcn_s_setprio(0);
    __builtin_amdgcn_s_barrier();

    // ---- P3: read A-half(wr) hi; stage B(t+2) (B slots free after P2 barrier); MFMA Q(1,1)
    LDA(buf, 1);
    if (t + 2 < NT) STAGE_B(buf);
    __builtin_amdgcn_s_barrier();
    asm volatile("s_waitcnt lgkmcnt(0)" ::: "memory");
    __builtin_amdgcn_sched_barrier(0);
    __builtin_amdgcn_s_setprio(1); MM(1, 1, bf1); __builtin_amdgcn_s_setprio(0);
    __builtin_amdgcn_s_barrier();

    // ---- P4: stage A(t+2) (A slots free after P3 barrier); MFMA Q(1,0) (regs only)
    if (t + 2 < NT) STAGE_A(buf);
    __builtin_amdgcn_s_barrier();
    __builtin_amdgcn_sched_barrier(0);
    __builtin_amdgcn_s_setprio(1); MM(1, 0, bf0); __builtin_amdgcn_s_setprio(0);
    // loop-top vmcnt+barrier separates iterations
  }

  // epilogue: C/D layout col=lane&15, row=(lane>>4)*4+reg  [verified m89/m91]
  #pragma unroll
  for (int mi = 0; mi < 8; mi++) {
    int rb = wr * 128 + mi * 16 + q * 4;
    #pragma unroll
    for (int r = 0; r < 4; r++) {
      int gm = m0 + rb + r;
      if (gm < cnt) {
        size_t orow = (size_t)(off + gm) * HD;
        #pragma unroll
        for (int ni = 0; ni < 4; ni++) {
          int gn = n0 + wc * 64 + ni * 16 + rm;
          float v = acc[mi][ni][r] + bias[gn];
          if (MODE == 1) {
            float uv = bf2f(Uep[orow + gn]);
            float sg = v / (1.f + __expf(-v));   // silu
            v = sg * uv;
          }
          Out[orow + gn] = f2bf(v);
        }
      }
    }
  }
}

// ---------------- combine: out[t] = w0*eo[p0] + w1*eo[p1] + eo[8192+t]
__global__ __launch_bounds__(256) void k_combine(const unsigned short* __restrict__ eo,
                                                 const int* __restrict__ tok_pos,
                                                 const float* __restrict__ wts,
                                                 float* __restrict__ out) {
  int t = blockIdx.x;
  int h = threadIdx.x * 8;
  int p0 = tok_pos[2*t], p1 = tok_pos[2*t+1];
  float w0 = wts[2*t], w1 = wts[2*t+1];
  u16x8 a = *(const u16x8*)(eo + (size_t)p0 * HD + h);
  u16x8 b = *(const u16x8*)(eo + (size_t)p1 * HD + h);
  u16x8 c = *(const u16x8*)(eo + (size_t)(ROWS_ROUTED + t) * HD + h);
  float* o = out + (size_t)t * HD + h;
  #pragma unroll
  for (int i = 0; i < 8; i++) o[i] = w0 * bf2f(a[i]) + w1 * bf2f(b[i]) + bf2f(c[i]);
}

extern "C" void kernel_launch(void* const* d_in, const int* in_sizes, int n_in,
                              void* d_out, int out_size, void* d_ws, size_t ws_size,
                              hipStream_t stream) {
  (void)in_sizes; (void)n_in; (void)out_size; (void)ws_size;
  const float* x     = (const float*)d_in[0];
  const float* Wr    = (const float*)d_in[1];
  const float* br    = (const float*)d_in[2];
  const float* gbias = (const float*)d_in[3];
  const float* Wup   = (const float*)d_in[4];
  const float* bup   = (const float*)d_in[5];
  const float* Wgate = (const float*)d_in[6];
  const float* bgate = (const float*)d_in[7];
  const float* Wdown = (const float*)d_in[8];
  const float* bdown = (const float*)d_in[9];
  const float* Wsu   = (const float*)d_in[10];
  const float* bsu   = (const float*)d_in[11];
  const float* Wsg   = (const float*)d_in[12];
  const float* bsg   = (const float*)d_in[13];
  const float* Wsd   = (const float*)d_in[14];
  const float* bsd   = (const float*)d_in[15];
  float* out = (float*)d_out;

  char* ws = (char*)d_ws;
  size_t o = 0;
  auto alloc = [&](size_t bytes) { char* p = ws + o; o += (bytes + 255) & ~(size_t)255; return p; };
  unsigned short* WT_r = (unsigned short*)alloc((size_t)7 * HD * HD * 2);
  unsigned short* WT_s = (unsigned short*)alloc((size_t)HD * HD * 2);
  unsigned short* xbf  = (unsigned short*)alloc((size_t)NTOK * HD * 2);
  unsigned short* bufU = (unsigned short*)alloc((size_t)ROWS_PAD * HD * 2);
  unsigned short* bufG = (unsigned short*)alloc((size_t)ROWS_PAD * HD * 2);
  int*   ctrl     = (int*)alloc(4096);
  int*   ids      = (int*)alloc(NTOK * 2 * 4);
  float* wts      = (float*)alloc(NTOK * 2 * 4);
  int*   tok_list = (int*)alloc(ROWS_TOTAL * 4);
  int*   tok_pos  = (int*)alloc(NTOK * 2 * 4);

  static bool attr_done = false;
  if (!attr_done) {
    hipFuncSetAttribute(reinterpret_cast<const void*>(&k_moe_gemm<0>),
                        hipFuncAttributeMaxDynamicSharedMemorySize, 131072);
    hipFuncSetAttribute(reinterpret_cast<const void*>(&k_moe_gemm<1>),
                        hipFuncAttributeMaxDynamicSharedMemorySize, 131072);
    hipFuncSetAttribute(reinterpret_cast<const void*>(&k_moe_gemm<2>),
                        hipFuncAttributeMaxDynamicSharedMemorySize, 131072);
    attr_done = true;
  }

  hipMemsetAsync(ctrl, 0, 96, stream);
  k_convert_bf16<<<NTOK * HD / 1024, 256, 0, stream>>>(x, xbf, NTOK * HD);
  k_router<<<NTOK / 4, 256, 0, stream>>>(x, Wr, br, gbias, ids, wts, ctrl);
  k_offsets<<<1, 64, 0, stream>>>(ctrl);
  k_build_lists<<<NTOK / 256, 256, 0, stream>>>(ids, ctrl, tok_list, tok_pos);

  dim3 tgrid(HD / 64, HD / 64, NEXP);
  dim3 ggrid(HD / BN, 4096 / BM, NEXP);   // x: 8 N-panels (XCD-affine), y: 16 M-tiles, z: experts

  k_transpose_bf16<<<tgrid, 256, 0, stream>>>(Wup, Wsu, WT_r, WT_s);
  k_moe_gemm<0><<<ggrid, 512, 131072, stream>>>(xbf, WT_r, WT_s, bup, bsu, ctrl, tok_list, nullptr, bufU);

  k_transpose_bf16<<<tgrid, 256, 0, stream>>>(Wgate, Wsg, WT_r, WT_s);
  k_moe_gemm<1><<<ggrid, 512, 131072, stream>>>(bufU, WT_r, WT_s, bgate, bsg, ctrl, tok_list, bufU, bufG);

  k_transpose_bf16<<<tgrid, 256, 0, stream>>>(Wdown, Wsd, WT_r, WT_s);
  k_moe_gemm<2><<<ggrid, 512, 131072, stream>>>(bufG, WT_r, WT_s, bdown, bsd, ctrl, tok_list, nullptr, bufU);

  k_combine<<<NTOK, 256, 0, stream>>>(bufU, tok_pos, wts, out);
}